// Round 11
// baseline (348.577 us; speedup 1.0000x reference)
//
#include <hip/hip_runtime.h>
#include <math.h>
#include <type_traits>

// ---------------------------------------------------------------------------
// NodeClsGAT: 3-layer GATConv (single head, PyG defaults) on MI355X.
// CSR build via 2-level bucket sort (R2). GEMM via MFMA 16x16x32_f16 (R10).
// k_agg R11: SINGLE-PASS softmax (no max-subtraction; shift-invariant, scores
// O(10) << 88 overflow bound). R10 counters (VALU 34%, HBM 27%) showed agg64
// still chain-latency-bound: the scores prologue (csr load -> asb gather ->
// 5-step max butterfly -> exp -> 5-step dsum butterfly) serialized ahead of
// every gather. Now scoring is fused into the gather loop (csr+asb broadcast
// loads per group); the existing cross-group butterfly merges dsum too.
// Slow path (deg>32, P~2e-4) keeps the proven two-pass max version.
// ---------------------------------------------------------------------------

#define NEG_SLOPE 0.2f
#define BKT_BITS 9          // 512 nodes per bucket; supports N <= 262144
#define BKT_SZ   512
#define PACK_SRC_BITS 20    // src < 2^20 (N = 100000)

typedef _Float16 h8v __attribute__((ext_vector_type(8)));
typedef _Float16 h4v __attribute__((ext_vector_type(4)));
typedef float f4v __attribute__((ext_vector_type(4)));

// ---------------- CSR build: pass A — bucket histogram ----------------
__global__ void k_zero(int* p, int n) {
    int i = blockIdx.x * blockDim.x + threadIdx.x;
    if (i < n) p[i] = 0;
}

__global__ __launch_bounds__(256) void k_hist(const int* __restrict__ dst, int E,
                                              int nb, int* __restrict__ bcount) {
    __shared__ int h[BKT_SZ];
    for (int i = threadIdx.x; i < nb; i += 256) h[i] = 0;
    __syncthreads();
    for (int i = blockIdx.x * 256 + threadIdx.x; i < E; i += gridDim.x * 256)
        atomicAdd(&h[dst[i] >> BKT_BITS], 1);
    __syncthreads();
    for (int i = threadIdx.x; i < nb; i += 256)
        if (h[i]) atomicAdd(&bcount[i], h[i]);
}

// ---------------- pass A2 — scan bucket counts (single block) ----------
__global__ __launch_bounds__(512) void k_bscan(const int* __restrict__ bcount, int nb,
                                               int E, int N, int* __restrict__ ebase,
                                               int* __restrict__ gcur,
                                               int* __restrict__ rowptr) {
    __shared__ int sm[BKT_SZ];
    int t = threadIdx.x;
    int v = (t < nb) ? bcount[t] : 0;
    sm[t] = v;
    __syncthreads();
    for (int o = 1; o < BKT_SZ; o <<= 1) {
        int tv = (t >= o) ? sm[t - o] : 0;
        __syncthreads();
        sm[t] += tv;
        __syncthreads();
    }
    int excl = sm[t] - v;
    if (t < nb) {
        ebase[t] = excl;
        gcur[t] = excl;
    }
    if (t == nb - 1) ebase[nb] = excl + v;  // == E
    if (t == 0) rowptr[N] = E + N;
}

// ---------------- pass B — rank-scatter packed records into buckets -----
__global__ __launch_bounds__(1024) void k_bscatter(const int* __restrict__ src,
                                                   const int* __restrict__ dst, int E,
                                                   int nb, int* __restrict__ gcur,
                                                   int* __restrict__ ebuf) {
    __shared__ int lc[BKT_SZ];
    __shared__ int gb[BKT_SZ];
    for (int i = threadIdx.x; i < nb; i += 1024) lc[i] = 0;
    __syncthreads();
    int base = blockIdx.x * 8192;
    int bkt[8], rnk[8], pk[8];
#pragma unroll
    for (int j = 0; j < 8; j++) {
        int i = base + j * 1024 + threadIdx.x;
        bkt[j] = -1;
        if (i < E) {
            int d = dst[i];
            int s = src[i];
            int b = d >> BKT_BITS;
            bkt[j] = b;
            rnk[j] = atomicAdd(&lc[b], 1);
            pk[j] = ((d & (BKT_SZ - 1)) << PACK_SRC_BITS) | s;
        }
    }
    __syncthreads();
    for (int b = threadIdx.x; b < nb; b += 1024)
        if (lc[b]) gb[b] = atomicAdd(&gcur[b], lc[b]);
    __syncthreads();
#pragma unroll
    for (int j = 0; j < 8; j++)
        if (bkt[j] >= 0) ebuf[gb[bkt[j]] + rnk[j]] = pk[j];
}

// ---------------- pass C — per-bucket CSR finalize ----------------------
__global__ __launch_bounds__(512) void k_bcsr(const int* __restrict__ ebuf,
                                              const int* __restrict__ ebase, int N,
                                              int* __restrict__ rowptr,
                                              int* __restrict__ csr) {
    __shared__ int cnt[BKT_SZ];
    __shared__ int sm[BKT_SZ];
    int b = blockIdx.x;
    int t = threadIdx.x;
    int n0 = b << BKT_BITS;
    int nn = min(BKT_SZ, N - n0);
    cnt[t] = 0;
    __syncthreads();
    int e0 = ebase[b], e1 = ebase[b + 1];
    for (int i = e0 + t; i < e1; i += BKT_SZ)
        atomicAdd(&cnt[ebuf[i] >> PACK_SRC_BITS], 1);
    __syncthreads();
    int v = cnt[t] + (t < nn ? 1 : 0);  // +1 self-loop slot per valid node
    sm[t] = v;
    __syncthreads();
    for (int o = 1; o < BKT_SZ; o <<= 1) {
        int tv = (t >= o) ? sm[t - o] : 0;
        __syncthreads();
        sm[t] += tv;
        __syncthreads();
    }
    int excl = sm[t] - v;
    int cb = e0 + n0;  // csr base: edges before bucket + self-loops before bucket
    if (t < nn) {
        rowptr[n0 + t] = cb + excl;
        csr[cb + excl] = n0 + t;  // self-loop at slot 0 of the node's segment
    }
    cnt[t] = excl + 1;  // edge cursor (after self-loop)
    __syncthreads();
    for (int i = e0 + t; i < e1; i += BKT_SZ) {
        int p = ebuf[i];
        int dl = p >> PACK_SRC_BITS;
        int pos = atomicAdd(&cnt[dl], 1);
        csr[cb + pos] = p & ((1 << PACK_SRC_BITS) - 1);
    }
}

// ---------------- GEMM via MFMA: H = X @ W (fp16 out), fp32 alpha ----------
// Wave computes a 16-row x FP-col tile, K=64 in 2 MFMA k-steps. B (W) frags
// preloaded per wave. Epilogue: alpha partials butterfly-reduced in-quad.
template <int FP>
__global__ __launch_bounds__(256) void k_gemm(
    const float* __restrict__ X, const float* __restrict__ W,
    const float* __restrict__ a_s, const float* __restrict__ a_d,
    int N, int Freal,
    _Float16* __restrict__ H, float* __restrict__ asb, float* __restrict__ adb) {
    constexpr int NT = FP / 16;  // 16-col tiles
    int lane = threadIdx.x & 63;
    int quad = lane >> 4;
    int c16 = lane & 15;

    // B frags + alpha values (per-lane, W is 16KB L2/L1-hot)
    h8v bf[NT][2];
    float asv[NT], adv[NT];
#pragma unroll
    for (int nt = 0; nt < NT; nt++) {
        int n = nt * 16 + c16;
        bool ok = (n < Freal);
        asv[nt] = ok ? a_s[n] : 0.f;
        adv[nt] = ok ? a_d[n] : 0.f;
#pragma unroll
        for (int kt = 0; kt < 2; kt++)
#pragma unroll
            for (int j = 0; j < 8; j++) {
                int k = kt * 32 + quad * 8 + j;
                bf[nt][kt][j] = (_Float16)(ok ? W[k * Freal + n] : 0.f);
            }
    }

    int wid = (blockIdx.x * blockDim.x + threadIdx.x) >> 6;
    int nw = (gridDim.x * blockDim.x) >> 6;
    int ntile = (N + 15) >> 4;

    for (int t = wid; t < ntile; t += nw) {
        int m0 = t << 4;
        int row = m0 + c16;
        const float* xr = X + (size_t)min(row, N - 1) * 64;
        h8v af[2];
#pragma unroll
        for (int kt = 0; kt < 2; kt++) {
            f4v x0 = *(const f4v*)(xr + kt * 32 + quad * 8);
            f4v x1 = *(const f4v*)(xr + kt * 32 + quad * 8 + 4);
#pragma unroll
            for (int j = 0; j < 4; j++) {
                af[kt][j] = (_Float16)x0[j];
                af[kt][4 + j] = (_Float16)x1[j];
            }
        }
        f4v c[NT];
#pragma unroll
        for (int nt = 0; nt < NT; nt++) c[nt] = (f4v){0.f, 0.f, 0.f, 0.f};
#pragma unroll
        for (int kt = 0; kt < 2; kt++)
#pragma unroll
            for (int nt = 0; nt < NT; nt++)
                c[nt] = __builtin_amdgcn_mfma_f32_16x16x32_f16(af[kt], bf[nt][kt],
                                                               c[nt], 0, 0, 0);
        // store H (fp16): row = m0 + quad*4 + reg, col = nt*16 + c16
#pragma unroll
        for (int reg = 0; reg < 4; reg++) {
            int r = m0 + quad * 4 + reg;
            if (r < N) {
#pragma unroll
                for (int nt = 0; nt < NT; nt++)
                    H[(size_t)r * FP + nt * 16 + c16] = (_Float16)c[nt][reg];
            }
        }
        // alpha epilogue: reduce over cols (c16 butterfly within quad group)
        float ps[4], pd[4];
#pragma unroll
        for (int reg = 0; reg < 4; reg++) {
            ps[reg] = 0.f;
            pd[reg] = 0.f;
#pragma unroll
            for (int nt = 0; nt < NT; nt++) {
                ps[reg] = fmaf(c[nt][reg], asv[nt], ps[reg]);
                pd[reg] = fmaf(c[nt][reg], adv[nt], pd[reg]);
            }
        }
        for (int o = 1; o < 16; o <<= 1) {
#pragma unroll
            for (int reg = 0; reg < 4; reg++) {
                ps[reg] += __shfl_xor(ps[reg], o, 64);
                pd[reg] += __shfl_xor(pd[reg], o, 64);
            }
        }
        if (c16 == 0) {
#pragma unroll
            for (int reg = 0; reg < 4; reg++) {
                int r = m0 + quad * 4 + reg;
                if (r < N) {
                    asb[r] = ps[reg];
                    adb[r] = pd[reg];
                }
            }
        }
    }
}

// ---------------- slow-path agg (R4-proven, whole wave, any deg) -----------
template <int FP>
__device__ __forceinline__ void agg_slow(
    int node, const _Float16* __restrict__ H, const float* __restrict__ asb,
    const float* __restrict__ adb, const float* __restrict__ bias,
    const int* __restrict__ rowptr, const int* __restrict__ csr,
    int N, int Freal, float* __restrict__ out, int mode, int lane) {
    if (node >= N) return;
    int start = rowptr[node];
    int end = rowptr[node + 1];
    float ad = adb[node];
    int lf = lane & (FP - 1);
    const float NEG_INF = -__builtin_inff();

    float m = NEG_INF;
    for (int base = start; base < end; base += 64) {
        int i = base + lane;
        if (i < end) {
            float t = asb[csr[i]] + ad;
            float e = (t > 0.f) ? t : NEG_SLOPE * t;
            m = fmaxf(m, e);
        }
    }
    for (int o = 32; o > 0; o >>= 1) m = fmaxf(m, __shfl_xor(m, o, 64));
    float dsum = 0.f, acc = 0.f;
    for (int base = start; base < end; base += 64) {
        int i = base + lane;
        int cnt = min(64, end - base);
        int s = 0;
        float p = 0.f;
        if (i < end) {
            s = csr[i];
            float t = asb[s] + ad;
            float e = (t > 0.f) ? t : NEG_SLOPE * t;
            p = __expf(e - m);
        }
        dsum += p;
        for (int j = 0; j < cnt; j++) {
            float pj = __shfl(p, j, 64);
            int sj = __shfl(s, j, 64);
            acc = fmaf(pj, (float)H[(size_t)sj * FP + lf], acc);
        }
    }
    for (int o = 32; o > 0; o >>= 1) dsum += __shfl_xor(dsum, o, 64);

    float b = (lf < Freal) ? bias[lf] : 0.f;
    float z = acc / dsum + b;
    if (mode == 0) {
        if (lane < FP) out[(size_t)node * FP + lane] = fmaxf(z, 0.f);
    } else {
        float zz = (lane < Freal) ? z : NEG_INF;
        float zm = zz;
        for (int o = 32; o > 0; o >>= 1) zm = fmaxf(zm, __shfl_xor(zm, o, 64));
        float ez = (lane < Freal) ? __expf(zz - zm) : 0.f;
        float es = ez;
        for (int o = 32; o > 0; o >>= 1) es += __shfl_xor(es, o, 64);
        if (lane < Freal) out[(size_t)node * Freal + lane] = zz - zm - __logf(es);
    }
}

// ---------------- Aggregation: dual-node wave, single-pass softmax ---------
// Half h owns node 2*wid+h (deg<=32 fast path). R11: no scores prologue —
// each group loads csr+asb (broadcast, L2-hot) inside the gather loop and
// computes p=exp(leaky(asb[s]+ad)) inline (no max-subtraction; safe while
// |score| << 88). Cross-group butterfly merges acc AND dsum. Overshoot
// lanes (idx >= deg) contribute p=0 with s=0 (valid address).
template <int FP, int W>
__global__ __launch_bounds__(256) void k_agg(
    const _Float16* __restrict__ H, const float* __restrict__ asb,
    const float* __restrict__ adb, const float* __restrict__ bias,
    const int* __restrict__ rowptr, const int* __restrict__ csr,
    int N, int Freal, float* __restrict__ out, int mode) {
    constexpr int LPR = FP / W;    // lanes per row (within a half)
    constexpr int GRPH = 32 / LPR; // rows in flight per half
    using vecW = typename std::conditional<W == 8, h8v, h4v>::type;
    int lane = threadIdx.x & 63;
    int half = lane >> 5;
    int li = lane & 31;
    int wid = (blockIdx.x * blockDim.x + threadIdx.x) >> 6;
    int nA = 2 * wid;
    if (nA >= N) return;
    int n = nA + half;
    bool valid = (n < N);
    int start = 0, end = 0;
    float ad = 0.f;
    if (valid) {
        start = rowptr[n];
        end = rowptr[n + 1];
        ad = adb[n];
    }
    int deg = end - start;
    int degm = max(deg, __shfl_xor(deg, 32, 64));  // wave-uniform

    const float NEG_INF = -__builtin_inff();

    if (degm <= 32) {
        int g = li / LPR;   // row-group within half
        int fl = li % LPR;  // vecW slot within row
        float acc[W];
#pragma unroll
        for (int c = 0; c < W; c++) acc[c] = 0.f;
        float dsum = 0.f;
#pragma unroll 2
        for (int jb = 0; jb < degm; jb += GRPH) {  // wave-uniform bound
            int idx = jb + g;
            bool ve = (idx < deg);                 // deg=0 when !valid
            int s = ve ? csr[start + idx] : 0;     // group-broadcast load
            float e = asb[s] + ad;                 // L2-hot broadcast load
            e = (e > 0.f) ? e : NEG_SLOPE * e;
            float p = ve ? __expf(e) : 0.f;        // no max-sub (|e| << 88)
            vecW r = ((const vecW*)(H + (size_t)s * FP))[fl];
            dsum += p;
#pragma unroll
            for (int c = 0; c < W; c++) acc[c] = fmaf(p, (float)r[c], acc[c]);
        }
        // cross-group butterfly within half: offsets LPR..16 preserve fl;
        // merges both acc and dsum (group-partial sums).
        for (int o = LPR; o < 32; o <<= 1) {
            dsum += __shfl_xor(dsum, o, 64);
#pragma unroll
            for (int c = 0; c < W; c++) acc[c] += __shfl_xor(acc[c], o, 64);
        }
        float inv = 1.f / dsum;
        int fbase = fl * W;

        if (mode == 0) {
            if (valid && li < LPR) {
                float z[W];
#pragma unroll
                for (int c = 0; c < W; c++)
                    z[c] = fmaxf(fmaf(acc[c], inv, bias[fbase + c]), 0.f);
                float4* op = (float4*)(out + (size_t)n * FP + fbase);
#pragma unroll
                for (int q = 0; q < W / 4; q++)
                    op[q] = make_float4(z[4 * q], z[4 * q + 1], z[4 * q + 2],
                                        z[4 * q + 3]);
            }
        } else {
            float zc[W];
#pragma unroll
            for (int c = 0; c < W; c++) {
                int f = fbase + c;
                zc[c] = (f < Freal) ? fmaf(acc[c], inv, bias[f]) : NEG_INF;
            }
            float vm = zc[0];
#pragma unroll
            for (int c = 1; c < W; c++) vm = fmaxf(vm, zc[c]);
            for (int o = 1; o < LPR; o <<= 1) vm = fmaxf(vm, __shfl_xor(vm, o, 64));
            float es = 0.f;
#pragma unroll
            for (int c = 0; c < W; c++) es += __expf(zc[c] - vm);
            for (int o = 1; o < LPR; o <<= 1) es += __shfl_xor(es, o, 64);
            float ls = __logf(es);
            if (valid && li < LPR) {
#pragma unroll
                for (int c = 0; c < W; c++) {
                    int f = fbase + c;
                    if (f < Freal) out[(size_t)n * Freal + f] = zc[c] - vm - ls;
                }
            }
        }
    } else {
        // rare (P(deg>32) ~ 2e-4): whole-wave per node, R4-proven path
        agg_slow<FP>(nA, H, asb, adb, bias, rowptr, csr, N, Freal, out, mode, lane);
        agg_slow<FP>(nA + 1, H, asb, adb, bias, rowptr, csr, N, Freal, out, mode, lane);
    }
}

// ---------------------------------------------------------------------------
extern "C" void kernel_launch(void* const* d_in, const int* in_sizes, int n_in,
                              void* d_out, int out_size, void* d_ws, size_t ws_size,
                              hipStream_t stream) {
    const float* x = (const float*)d_in[0];
    const int* ei = (const int*)d_in[1];
    const float* W1 = (const float*)d_in[2];
    const float* a1s = (const float*)d_in[3];
    const float* a1d = (const float*)d_in[4];
    const float* b1 = (const float*)d_in[5];
    const float* W2 = (const float*)d_in[6];
    const float* a2s = (const float*)d_in[7];
    const float* a2d = (const float*)d_in[8];
    const float* b2 = (const float*)d_in[9];
    const float* W3 = (const float*)d_in[10];
    const float* a3s = (const float*)d_in[11];
    const float* a3d = (const float*)d_in[12];
    const float* b3 = (const float*)d_in[13];

    const int N = in_sizes[0] / 64;
    const int E = in_sizes[1] / 2;
    const int Etot = E + N;
    const int nb = (N + BKT_SZ - 1) >> BKT_BITS;  // buckets of 512 nodes
    const int* srcv = ei;
    const int* dstv = ei + E;

    // workspace carve (256B aligned)
    size_t off = 0;
    char* base = (char*)d_ws;
    auto carve = [&](size_t bytes) -> void* {
        void* p = base + off;
        off = (off + bytes + 255) & ~(size_t)255;
        return p;
    };
    int* bcount = (int*)carve((size_t)(nb + 1) * 4);
    int* ebase = (int*)carve((size_t)(nb + 1) * 4);
    int* gcur = (int*)carve((size_t)nb * 4);
    int* rowptr = (int*)carve((size_t)(N + 1) * 4);
    int* csr = (int*)carve((size_t)Etot * 4);
    float* asb = (float*)carve((size_t)N * 4);
    float* adb = (float*)carve((size_t)N * 4);
    _Float16* hA = (_Float16*)carve((size_t)N * 64 * 2);  // fp16 H (layers 1,2)
    float* fB = (float*)carve((size_t)N * 64 * 4);        // fp32 agg out / X
    _Float16* hC = (_Float16*)carve((size_t)N * 16 * 2);  // fp16 H (layer 3)
    int* ebuf = (int*)hA;  // alias: ebuf (E*4 <= N*64*2) only live pre-layer-1

    // ---- CSR build (bucket sort) ----
    k_zero<<<(nb + 255) / 256, 256, 0, stream>>>(bcount, nb);
    k_hist<<<512, 256, 0, stream>>>(dstv, E, nb, bcount);
    k_bscan<<<1, BKT_SZ, 0, stream>>>(bcount, nb, E, N, ebase, gcur, rowptr);
    k_bscatter<<<(E + 8191) / 8192, 1024, 0, stream>>>(srcv, dstv, E, nb, gcur, ebuf);
    k_bcsr<<<nb, BKT_SZ, 0, stream>>>(ebuf, ebase, N, rowptr, csr);

    const int aggBlocks = (N + 7) / 8;  // 4 waves/block, 2 nodes/wave
    const int gemmBlocks = 784;        // 3136 waves, ~2 tiles (16 rows) each

    // ---- layer 1 ----
    k_gemm<64><<<gemmBlocks, 256, 0, stream>>>(x, W1, a1s, a1d, N, 64, hA, asb, adb);
    k_agg<64, 8><<<aggBlocks, 256, 0, stream>>>(hA, asb, adb, b1, rowptr, csr, N, 64, fB, 0);
    // ---- layer 2 ----
    k_gemm<64><<<gemmBlocks, 256, 0, stream>>>(fB, W2, a2s, a2d, N, 64, hA, asb, adb);
    k_agg<64, 8><<<aggBlocks, 256, 0, stream>>>(hA, asb, adb, b2, rowptr, csr, N, 64, fB, 0);
    // ---- layer 3 ----
    k_gemm<16><<<gemmBlocks, 256, 0, stream>>>(fB, W3, a3s, a3d, N, 10, hC, asb, adb);
    k_agg<16, 4><<<aggBlocks, 256, 0, stream>>>(hC, asb, adb, b3, rowptr, csr, N, 10,
                                                (float*)d_out, 1);
}

// Round 12
// 341.931 us; speedup vs baseline: 1.0194x; 1.0194x over previous
//
#include <hip/hip_runtime.h>
#include <math.h>
#include <type_traits>

// ---------------------------------------------------------------------------
// NodeClsGAT: 3-layer GATConv (single head, PyG defaults) on MI355X.
// CSR build via 2-level bucket sort (R2). GEMM via MFMA 16x16x32_f16 (R10).
// k_agg: R10's two-phase version (scores phase -> register-fed gather loop).
// R11's single-pass fusion REGRESSED (54->60us): it put csr->asb dependent
// loads inside every gather iteration — do not re-add in-loop load deps.
// R12: revert agg to R10; k_zero dispatch replaced by hipMemsetAsync.
// ---------------------------------------------------------------------------

#define NEG_SLOPE 0.2f
#define BKT_BITS 9          // 512 nodes per bucket; supports N <= 262144
#define BKT_SZ   512
#define PACK_SRC_BITS 20    // src < 2^20 (N = 100000)

typedef _Float16 h8v __attribute__((ext_vector_type(8)));
typedef _Float16 h4v __attribute__((ext_vector_type(4)));
typedef float f4v __attribute__((ext_vector_type(4)));

// ---------------- CSR build: pass A — bucket histogram ----------------
__global__ __launch_bounds__(256) void k_hist(const int* __restrict__ dst, int E,
                                              int nb, int* __restrict__ bcount) {
    __shared__ int h[BKT_SZ];
    for (int i = threadIdx.x; i < nb; i += 256) h[i] = 0;
    __syncthreads();
    for (int i = blockIdx.x * 256 + threadIdx.x; i < E; i += gridDim.x * 256)
        atomicAdd(&h[dst[i] >> BKT_BITS], 1);
    __syncthreads();
    for (int i = threadIdx.x; i < nb; i += 256)
        if (h[i]) atomicAdd(&bcount[i], h[i]);
}

// ---------------- pass A2 — scan bucket counts (single block) ----------
__global__ __launch_bounds__(512) void k_bscan(const int* __restrict__ bcount, int nb,
                                               int E, int N, int* __restrict__ ebase,
                                               int* __restrict__ gcur,
                                               int* __restrict__ rowptr) {
    __shared__ int sm[BKT_SZ];
    int t = threadIdx.x;
    int v = (t < nb) ? bcount[t] : 0;
    sm[t] = v;
    __syncthreads();
    for (int o = 1; o < BKT_SZ; o <<= 1) {
        int tv = (t >= o) ? sm[t - o] : 0;
        __syncthreads();
        sm[t] += tv;
        __syncthreads();
    }
    int excl = sm[t] - v;
    if (t < nb) {
        ebase[t] = excl;
        gcur[t] = excl;
    }
    if (t == nb - 1) ebase[nb] = excl + v;  // == E
    if (t == 0) rowptr[N] = E + N;
}

// ---------------- pass B — rank-scatter packed records into buckets -----
__global__ __launch_bounds__(1024) void k_bscatter(const int* __restrict__ src,
                                                   const int* __restrict__ dst, int E,
                                                   int nb, int* __restrict__ gcur,
                                                   int* __restrict__ ebuf) {
    __shared__ int lc[BKT_SZ];
    __shared__ int gb[BKT_SZ];
    for (int i = threadIdx.x; i < nb; i += 1024) lc[i] = 0;
    __syncthreads();
    int base = blockIdx.x * 8192;
    int bkt[8], rnk[8], pk[8];
#pragma unroll
    for (int j = 0; j < 8; j++) {
        int i = base + j * 1024 + threadIdx.x;
        bkt[j] = -1;
        if (i < E) {
            int d = dst[i];
            int s = src[i];
            int b = d >> BKT_BITS;
            bkt[j] = b;
            rnk[j] = atomicAdd(&lc[b], 1);
            pk[j] = ((d & (BKT_SZ - 1)) << PACK_SRC_BITS) | s;
        }
    }
    __syncthreads();
    for (int b = threadIdx.x; b < nb; b += 1024)
        if (lc[b]) gb[b] = atomicAdd(&gcur[b], lc[b]);
    __syncthreads();
#pragma unroll
    for (int j = 0; j < 8; j++)
        if (bkt[j] >= 0) ebuf[gb[bkt[j]] + rnk[j]] = pk[j];
}

// ---------------- pass C — per-bucket CSR finalize ----------------------
__global__ __launch_bounds__(512) void k_bcsr(const int* __restrict__ ebuf,
                                              const int* __restrict__ ebase, int N,
                                              int* __restrict__ rowptr,
                                              int* __restrict__ csr) {
    __shared__ int cnt[BKT_SZ];
    __shared__ int sm[BKT_SZ];
    int b = blockIdx.x;
    int t = threadIdx.x;
    int n0 = b << BKT_BITS;
    int nn = min(BKT_SZ, N - n0);
    cnt[t] = 0;
    __syncthreads();
    int e0 = ebase[b], e1 = ebase[b + 1];
    for (int i = e0 + t; i < e1; i += BKT_SZ)
        atomicAdd(&cnt[ebuf[i] >> PACK_SRC_BITS], 1);
    __syncthreads();
    int v = cnt[t] + (t < nn ? 1 : 0);  // +1 self-loop slot per valid node
    sm[t] = v;
    __syncthreads();
    for (int o = 1; o < BKT_SZ; o <<= 1) {
        int tv = (t >= o) ? sm[t - o] : 0;
        __syncthreads();
        sm[t] += tv;
        __syncthreads();
    }
    int excl = sm[t] - v;
    int cb = e0 + n0;  // csr base: edges before bucket + self-loops before bucket
    if (t < nn) {
        rowptr[n0 + t] = cb + excl;
        csr[cb + excl] = n0 + t;  // self-loop at slot 0 of the node's segment
    }
    cnt[t] = excl + 1;  // edge cursor (after self-loop)
    __syncthreads();
    for (int i = e0 + t; i < e1; i += BKT_SZ) {
        int p = ebuf[i];
        int dl = p >> PACK_SRC_BITS;
        int pos = atomicAdd(&cnt[dl], 1);
        csr[cb + pos] = p & ((1 << PACK_SRC_BITS) - 1);
    }
}

// ---------------- GEMM via MFMA: H = X @ W (fp16 out), fp32 alpha ----------
// Wave computes a 16-row x FP-col tile, K=64 in 2 MFMA k-steps. B (W) frags
// preloaded per wave. Epilogue: alpha partials butterfly-reduced in-quad.
template <int FP>
__global__ __launch_bounds__(256) void k_gemm(
    const float* __restrict__ X, const float* __restrict__ W,
    const float* __restrict__ a_s, const float* __restrict__ a_d,
    int N, int Freal,
    _Float16* __restrict__ H, float* __restrict__ asb, float* __restrict__ adb) {
    constexpr int NT = FP / 16;  // 16-col tiles
    int lane = threadIdx.x & 63;
    int quad = lane >> 4;
    int c16 = lane & 15;

    // B frags + alpha values (per-lane, W is 16KB L2/L1-hot)
    h8v bf[NT][2];
    float asv[NT], adv[NT];
#pragma unroll
    for (int nt = 0; nt < NT; nt++) {
        int n = nt * 16 + c16;
        bool ok = (n < Freal);
        asv[nt] = ok ? a_s[n] : 0.f;
        adv[nt] = ok ? a_d[n] : 0.f;
#pragma unroll
        for (int kt = 0; kt < 2; kt++)
#pragma unroll
            for (int j = 0; j < 8; j++) {
                int k = kt * 32 + quad * 8 + j;
                bf[nt][kt][j] = (_Float16)(ok ? W[k * Freal + n] : 0.f);
            }
    }

    int wid = (blockIdx.x * blockDim.x + threadIdx.x) >> 6;
    int nw = (gridDim.x * blockDim.x) >> 6;
    int ntile = (N + 15) >> 4;

    for (int t = wid; t < ntile; t += nw) {
        int m0 = t << 4;
        int row = m0 + c16;
        const float* xr = X + (size_t)min(row, N - 1) * 64;
        h8v af[2];
#pragma unroll
        for (int kt = 0; kt < 2; kt++) {
            f4v x0 = *(const f4v*)(xr + kt * 32 + quad * 8);
            f4v x1 = *(const f4v*)(xr + kt * 32 + quad * 8 + 4);
#pragma unroll
            for (int j = 0; j < 4; j++) {
                af[kt][j] = (_Float16)x0[j];
                af[kt][4 + j] = (_Float16)x1[j];
            }
        }
        f4v c[NT];
#pragma unroll
        for (int nt = 0; nt < NT; nt++) c[nt] = (f4v){0.f, 0.f, 0.f, 0.f};
#pragma unroll
        for (int kt = 0; kt < 2; kt++)
#pragma unroll
            for (int nt = 0; nt < NT; nt++)
                c[nt] = __builtin_amdgcn_mfma_f32_16x16x32_f16(af[kt], bf[nt][kt],
                                                               c[nt], 0, 0, 0);
        // store H (fp16): row = m0 + quad*4 + reg, col = nt*16 + c16
#pragma unroll
        for (int reg = 0; reg < 4; reg++) {
            int r = m0 + quad * 4 + reg;
            if (r < N) {
#pragma unroll
                for (int nt = 0; nt < NT; nt++)
                    H[(size_t)r * FP + nt * 16 + c16] = (_Float16)c[nt][reg];
            }
        }
        // alpha epilogue: reduce over cols (c16 butterfly within quad group)
        float ps[4], pd[4];
#pragma unroll
        for (int reg = 0; reg < 4; reg++) {
            ps[reg] = 0.f;
            pd[reg] = 0.f;
#pragma unroll
            for (int nt = 0; nt < NT; nt++) {
                ps[reg] = fmaf(c[nt][reg], asv[nt], ps[reg]);
                pd[reg] = fmaf(c[nt][reg], adv[nt], pd[reg]);
            }
        }
        for (int o = 1; o < 16; o <<= 1) {
#pragma unroll
            for (int reg = 0; reg < 4; reg++) {
                ps[reg] += __shfl_xor(ps[reg], o, 64);
                pd[reg] += __shfl_xor(pd[reg], o, 64);
            }
        }
        if (c16 == 0) {
#pragma unroll
            for (int reg = 0; reg < 4; reg++) {
                int r = m0 + quad * 4 + reg;
                if (r < N) {
                    asb[r] = ps[reg];
                    adb[r] = pd[reg];
                }
            }
        }
    }
}

// ---------------- slow-path agg (R4-proven, whole wave, any deg) -----------
template <int FP>
__device__ __forceinline__ void agg_slow(
    int node, const _Float16* __restrict__ H, const float* __restrict__ asb,
    const float* __restrict__ adb, const float* __restrict__ bias,
    const int* __restrict__ rowptr, const int* __restrict__ csr,
    int N, int Freal, float* __restrict__ out, int mode, int lane) {
    if (node >= N) return;
    int start = rowptr[node];
    int end = rowptr[node + 1];
    float ad = adb[node];
    int lf = lane & (FP - 1);
    const float NEG_INF = -__builtin_inff();

    float m = NEG_INF;
    for (int base = start; base < end; base += 64) {
        int i = base + lane;
        if (i < end) {
            float t = asb[csr[i]] + ad;
            float e = (t > 0.f) ? t : NEG_SLOPE * t;
            m = fmaxf(m, e);
        }
    }
    for (int o = 32; o > 0; o >>= 1) m = fmaxf(m, __shfl_xor(m, o, 64));
    float dsum = 0.f, acc = 0.f;
    for (int base = start; base < end; base += 64) {
        int i = base + lane;
        int cnt = min(64, end - base);
        int s = 0;
        float p = 0.f;
        if (i < end) {
            s = csr[i];
            float t = asb[s] + ad;
            float e = (t > 0.f) ? t : NEG_SLOPE * t;
            p = __expf(e - m);
        }
        dsum += p;
        for (int j = 0; j < cnt; j++) {
            float pj = __shfl(p, j, 64);
            int sj = __shfl(s, j, 64);
            acc = fmaf(pj, (float)H[(size_t)sj * FP + lf], acc);
        }
    }
    for (int o = 32; o > 0; o >>= 1) dsum += __shfl_xor(dsum, o, 64);

    float b = (lf < Freal) ? bias[lf] : 0.f;
    float z = acc / dsum + b;
    if (mode == 0) {
        if (lane < FP) out[(size_t)node * FP + lane] = fmaxf(z, 0.f);
    } else {
        float zz = (lane < Freal) ? z : NEG_INF;
        float zm = zz;
        for (int o = 32; o > 0; o >>= 1) zm = fmaxf(zm, __shfl_xor(zm, o, 64));
        float ez = (lane < Freal) ? __expf(zz - zm) : 0.f;
        float es = ez;
        for (int o = 32; o > 0; o >>= 1) es += __shfl_xor(es, o, 64);
        if (lane < Freal) out[(size_t)node * Freal + lane] = zz - zm - __logf(es);
    }
}

// ---------------- Aggregation: dual-node wave, vector gather (R10) ---------
// Half h of the wave owns node 2*wid+h (deg<=32 fast path). Scores + max/
// dsum butterflies within the 32-lane half (offsets 16..1). Gather: LPR
// lanes/row, GRPH=32/LPR rows in flight per half, W halfs (2W bytes)/lane.
// Loop bound degm = max(degA,degB) is wave-uniform; shuffle index
// half*32+jb+g <= half*32+31 stays in-half; overshoot lanes get p=0,s=0.
template <int FP, int W>
__global__ __launch_bounds__(256) void k_agg(
    const _Float16* __restrict__ H, const float* __restrict__ asb,
    const float* __restrict__ adb, const float* __restrict__ bias,
    const int* __restrict__ rowptr, const int* __restrict__ csr,
    int N, int Freal, float* __restrict__ out, int mode) {
    constexpr int LPR = FP / W;    // lanes per row (within a half)
    constexpr int GRPH = 32 / LPR; // rows in flight per half
    using vecW = typename std::conditional<W == 8, h8v, h4v>::type;
    int lane = threadIdx.x & 63;
    int half = lane >> 5;
    int li = lane & 31;
    int wid = (blockIdx.x * blockDim.x + threadIdx.x) >> 6;
    int nA = 2 * wid;
    if (nA >= N) return;
    int n = nA + half;
    bool valid = (n < N);
    int start = 0, end = 0;
    float ad = 0.f;
    if (valid) {
        start = rowptr[n];
        end = rowptr[n + 1];
        ad = adb[n];
    }
    int deg = end - start;
    int degm = max(deg, __shfl_xor(deg, 32, 64));  // wave-uniform

    const float NEG_INF = -__builtin_inff();

    if (degm <= 32) {
        int g = li / LPR;   // row-group within half
        int fl = li % LPR;  // vecW slot within row
        int s = 0;
        float e = NEG_INF;
        if (li < deg) {
            s = csr[start + li];
            float t = asb[s] + ad;
            e = (t > 0.f) ? t : NEG_SLOPE * t;
        }
        float m = e;
        for (int o = 16; o > 0; o >>= 1) m = fmaxf(m, __shfl_xor(m, o, 64));
        float p = (li < deg) ? __expf(e - m) : 0.f;
        float dsum = p;
        for (int o = 16; o > 0; o >>= 1) dsum += __shfl_xor(dsum, o, 64);

        float acc[W];
#pragma unroll
        for (int c = 0; c < W; c++) acc[c] = 0.f;
#pragma unroll 2
        for (int jb = 0; jb < degm; jb += GRPH) {  // wave-uniform bound
            int gidx = half * 32 + jb + g;         // in-half, <= half*32+31
            float pj = __shfl(p, gidx, 64);        // 0 for jb+g >= deg
            int sj = __shfl(s, gidx, 64);          // 0 for jb+g >= deg
            vecW r = ((const vecW*)(H + (size_t)sj * FP))[fl];
#pragma unroll
            for (int c = 0; c < W; c++) acc[c] = fmaf(pj, (float)r[c], acc[c]);
        }
        // cross-group butterfly within half: offsets LPR..16 preserve fl
        for (int o = LPR; o < 32; o <<= 1) {
#pragma unroll
            for (int c = 0; c < W; c++) acc[c] += __shfl_xor(acc[c], o, 64);
        }
        float inv = 1.f / dsum;
        int fbase = fl * W;

        if (mode == 0) {
            if (valid && li < LPR) {
                float z[W];
#pragma unroll
                for (int c = 0; c < W; c++)
                    z[c] = fmaxf(fmaf(acc[c], inv, bias[fbase + c]), 0.f);
                float4* op = (float4*)(out + (size_t)n * FP + fbase);
#pragma unroll
                for (int q = 0; q < W / 4; q++)
                    op[q] = make_float4(z[4 * q], z[4 * q + 1], z[4 * q + 2],
                                        z[4 * q + 3]);
            }
        } else {
            float zc[W];
#pragma unroll
            for (int c = 0; c < W; c++) {
                int f = fbase + c;
                zc[c] = (f < Freal) ? fmaf(acc[c], inv, bias[f]) : NEG_INF;
            }
            float vm = zc[0];
#pragma unroll
            for (int c = 1; c < W; c++) vm = fmaxf(vm, zc[c]);
            for (int o = 1; o < LPR; o <<= 1) vm = fmaxf(vm, __shfl_xor(vm, o, 64));
            float es = 0.f;
#pragma unroll
            for (int c = 0; c < W; c++) es += __expf(zc[c] - vm);
            for (int o = 1; o < LPR; o <<= 1) es += __shfl_xor(es, o, 64);
            float ls = __logf(es);
            if (valid && li < LPR) {
#pragma unroll
                for (int c = 0; c < W; c++) {
                    int f = fbase + c;
                    if (f < Freal) out[(size_t)n * Freal + f] = zc[c] - vm - ls;
                }
            }
        }
    } else {
        // rare (P(deg>32) ~ 2e-4): whole-wave per node, R4-proven path
        agg_slow<FP>(nA, H, asb, adb, bias, rowptr, csr, N, Freal, out, mode, lane);
        agg_slow<FP>(nA + 1, H, asb, adb, bias, rowptr, csr, N, Freal, out, mode, lane);
    }
}

// ---------------------------------------------------------------------------
extern "C" void kernel_launch(void* const* d_in, const int* in_sizes, int n_in,
                              void* d_out, int out_size, void* d_ws, size_t ws_size,
                              hipStream_t stream) {
    const float* x = (const float*)d_in[0];
    const int* ei = (const int*)d_in[1];
    const float* W1 = (const float*)d_in[2];
    const float* a1s = (const float*)d_in[3];
    const float* a1d = (const float*)d_in[4];
    const float* b1 = (const float*)d_in[5];
    const float* W2 = (const float*)d_in[6];
    const float* a2s = (const float*)d_in[7];
    const float* a2d = (const float*)d_in[8];
    const float* b2 = (const float*)d_in[9];
    const float* W3 = (const float*)d_in[10];
    const float* a3s = (const float*)d_in[11];
    const float* a3d = (const float*)d_in[12];
    const float* b3 = (const float*)d_in[13];

    const int N = in_sizes[0] / 64;
    const int E = in_sizes[1] / 2;
    const int Etot = E + N;
    const int nb = (N + BKT_SZ - 1) >> BKT_BITS;  // buckets of 512 nodes
    const int* srcv = ei;
    const int* dstv = ei + E;

    // workspace carve (256B aligned)
    size_t off = 0;
    char* base = (char*)d_ws;
    auto carve = [&](size_t bytes) -> void* {
        void* p = base + off;
        off = (off + bytes + 255) & ~(size_t)255;
        return p;
    };
    int* bcount = (int*)carve((size_t)(nb + 1) * 4);
    int* ebase = (int*)carve((size_t)(nb + 1) * 4);
    int* gcur = (int*)carve((size_t)nb * 4);
    int* rowptr = (int*)carve((size_t)(N + 1) * 4);
    int* csr = (int*)carve((size_t)Etot * 4);
    float* asb = (float*)carve((size_t)N * 4);
    float* adb = (float*)carve((size_t)N * 4);
    _Float16* hA = (_Float16*)carve((size_t)N * 64 * 2);  // fp16 H (layers 1,2)
    float* fB = (float*)carve((size_t)N * 64 * 4);        // fp32 agg out / X
    _Float16* hC = (_Float16*)carve((size_t)N * 16 * 2);  // fp16 H (layer 3)
    int* ebuf = (int*)hA;  // alias: ebuf (E*4 <= N*64*2) only live pre-layer-1

    // ---- CSR build (bucket sort) ----
    hipMemsetAsync(bcount, 0, (size_t)nb * 4, stream);  // replaces k_zero dispatch
    k_hist<<<512, 256, 0, stream>>>(dstv, E, nb, bcount);
    k_bscan<<<1, BKT_SZ, 0, stream>>>(bcount, nb, E, N, ebase, gcur, rowptr);
    k_bscatter<<<(E + 8191) / 8192, 1024, 0, stream>>>(srcv, dstv, E, nb, gcur, ebuf);
    k_bcsr<<<nb, BKT_SZ, 0, stream>>>(ebuf, ebase, N, rowptr, csr);

    const int aggBlocks = (N + 7) / 8;  // 4 waves/block, 2 nodes/wave
    const int gemmBlocks = 784;        // 3136 waves, ~2 tiles (16 rows) each

    // ---- layer 1 ----
    k_gemm<64><<<gemmBlocks, 256, 0, stream>>>(x, W1, a1s, a1d, N, 64, hA, asb, adb);
    k_agg<64, 8><<<aggBlocks, 256, 0, stream>>>(hA, asb, adb, b1, rowptr, csr, N, 64, fB, 0);
    // ---- layer 2 ----
    k_gemm<64><<<gemmBlocks, 256, 0, stream>>>(fB, W2, a2s, a2d, N, 64, hA, asb, adb);
    k_agg<64, 8><<<aggBlocks, 256, 0, stream>>>(hA, asb, adb, b2, rowptr, csr, N, 64, fB, 0);
    // ---- layer 3 ----
    k_gemm<16><<<gemmBlocks, 256, 0, stream>>>(fB, W3, a3s, a3d, N, 10, hC, asb, adb);
    k_agg<16, 4><<<aggBlocks, 256, 0, stream>>>(hC, asb, adb, b3, rowptr, csr, N, 10,
                                                (float*)d_out, 1);
}

// Round 13
// 329.507 us; speedup vs baseline: 1.0579x; 1.0377x over previous
//
#include <hip/hip_runtime.h>
#include <math.h>
#include <type_traits>

// ---------------------------------------------------------------------------
// NodeClsGAT: 3-layer GATConv (single head, PyG defaults) on MI355X.
// CSR build via 2-level bucket sort (R2). GEMM via MFMA 16x16x32_f16 (R10).
// k_agg: R10 two-phase (R11's in-loop load fusion regressed — keep loads out
// of the gather loop). R13: (a) k_hist fused with layer-1 GEMM in one
// partitioned-grid dispatch (gemm1 is independent of the CSR build chain —
// hide it under hist); (b) agg gather unroll 2->4 (32 rows in flight/wave).
// ---------------------------------------------------------------------------

#define NEG_SLOPE 0.2f
#define BKT_BITS 9          // 512 nodes per bucket; supports N <= 262144
#define BKT_SZ   512
#define PACK_SRC_BITS 20    // src < 2^20 (N = 100000)

typedef _Float16 h8v __attribute__((ext_vector_type(8)));
typedef _Float16 h4v __attribute__((ext_vector_type(4)));
typedef float f4v __attribute__((ext_vector_type(4)));

// ---------------- pass A2 — scan bucket counts (single block) ----------
__global__ __launch_bounds__(512) void k_bscan(const int* __restrict__ bcount, int nb,
                                               int E, int N, int* __restrict__ ebase,
                                               int* __restrict__ gcur,
                                               int* __restrict__ rowptr) {
    __shared__ int sm[BKT_SZ];
    int t = threadIdx.x;
    int v = (t < nb) ? bcount[t] : 0;
    sm[t] = v;
    __syncthreads();
    for (int o = 1; o < BKT_SZ; o <<= 1) {
        int tv = (t >= o) ? sm[t - o] : 0;
        __syncthreads();
        sm[t] += tv;
        __syncthreads();
    }
    int excl = sm[t] - v;
    if (t < nb) {
        ebase[t] = excl;
        gcur[t] = excl;
    }
    if (t == nb - 1) ebase[nb] = excl + v;  // == E
    if (t == 0) rowptr[N] = E + N;
}

// ---------------- pass B — rank-scatter packed records into buckets -----
__global__ __launch_bounds__(1024) void k_bscatter(const int* __restrict__ src,
                                                   const int* __restrict__ dst, int E,
                                                   int nb, int* __restrict__ gcur,
                                                   int* __restrict__ ebuf) {
    __shared__ int lc[BKT_SZ];
    __shared__ int gb[BKT_SZ];
    for (int i = threadIdx.x; i < nb; i += 1024) lc[i] = 0;
    __syncthreads();
    int base = blockIdx.x * 8192;
    int bkt[8], rnk[8], pk[8];
#pragma unroll
    for (int j = 0; j < 8; j++) {
        int i = base + j * 1024 + threadIdx.x;
        bkt[j] = -1;
        if (i < E) {
            int d = dst[i];
            int s = src[i];
            int b = d >> BKT_BITS;
            bkt[j] = b;
            rnk[j] = atomicAdd(&lc[b], 1);
            pk[j] = ((d & (BKT_SZ - 1)) << PACK_SRC_BITS) | s;
        }
    }
    __syncthreads();
    for (int b = threadIdx.x; b < nb; b += 1024)
        if (lc[b]) gb[b] = atomicAdd(&gcur[b], lc[b]);
    __syncthreads();
#pragma unroll
    for (int j = 0; j < 8; j++)
        if (bkt[j] >= 0) ebuf[gb[bkt[j]] + rnk[j]] = pk[j];
}

// ---------------- pass C — per-bucket CSR finalize ----------------------
__global__ __launch_bounds__(512) void k_bcsr(const int* __restrict__ ebuf,
                                              const int* __restrict__ ebase, int N,
                                              int* __restrict__ rowptr,
                                              int* __restrict__ csr) {
    __shared__ int cnt[BKT_SZ];
    __shared__ int sm[BKT_SZ];
    int b = blockIdx.x;
    int t = threadIdx.x;
    int n0 = b << BKT_BITS;
    int nn = min(BKT_SZ, N - n0);
    cnt[t] = 0;
    __syncthreads();
    int e0 = ebase[b], e1 = ebase[b + 1];
    for (int i = e0 + t; i < e1; i += BKT_SZ)
        atomicAdd(&cnt[ebuf[i] >> PACK_SRC_BITS], 1);
    __syncthreads();
    int v = cnt[t] + (t < nn ? 1 : 0);  // +1 self-loop slot per valid node
    sm[t] = v;
    __syncthreads();
    for (int o = 1; o < BKT_SZ; o <<= 1) {
        int tv = (t >= o) ? sm[t - o] : 0;
        __syncthreads();
        sm[t] += tv;
        __syncthreads();
    }
    int excl = sm[t] - v;
    int cb = e0 + n0;  // csr base: edges before bucket + self-loops before bucket
    if (t < nn) {
        rowptr[n0 + t] = cb + excl;
        csr[cb + excl] = n0 + t;  // self-loop at slot 0 of the node's segment
    }
    cnt[t] = excl + 1;  // edge cursor (after self-loop)
    __syncthreads();
    for (int i = e0 + t; i < e1; i += BKT_SZ) {
        int p = ebuf[i];
        int dl = p >> PACK_SRC_BITS;
        int pos = atomicAdd(&cnt[dl], 1);
        csr[cb + pos] = p & ((1 << PACK_SRC_BITS) - 1);
    }
}

// ---------------- GEMM body (FP=64, Freal=64) via MFMA, inlinable ----------
__device__ __forceinline__ void gemm64_body(
    int bid, int nblocks, const float* __restrict__ X, const float* __restrict__ W,
    const float* __restrict__ a_s, const float* __restrict__ a_d, int N,
    _Float16* __restrict__ H, float* __restrict__ asb, float* __restrict__ adb) {
    constexpr int NT = 4;
    int lane = threadIdx.x & 63;
    int quad = lane >> 4;
    int c16 = lane & 15;

    h8v bf[NT][2];
    float asv[NT], adv[NT];
#pragma unroll
    for (int nt = 0; nt < NT; nt++) {
        int n = nt * 16 + c16;
        asv[nt] = a_s[n];
        adv[nt] = a_d[n];
#pragma unroll
        for (int kt = 0; kt < 2; kt++)
#pragma unroll
            for (int j = 0; j < 8; j++) {
                int k = kt * 32 + quad * 8 + j;
                bf[nt][kt][j] = (_Float16)W[k * 64 + n];
            }
    }

    int wid = (bid * 256 + (int)threadIdx.x) >> 6;
    int nw = (nblocks * 256) >> 6;
    int ntile = (N + 15) >> 4;

    for (int t = wid; t < ntile; t += nw) {
        int m0 = t << 4;
        int row = m0 + c16;
        const float* xr = X + (size_t)min(row, N - 1) * 64;
        h8v af[2];
#pragma unroll
        for (int kt = 0; kt < 2; kt++) {
            f4v x0 = *(const f4v*)(xr + kt * 32 + quad * 8);
            f4v x1 = *(const f4v*)(xr + kt * 32 + quad * 8 + 4);
#pragma unroll
            for (int j = 0; j < 4; j++) {
                af[kt][j] = (_Float16)x0[j];
                af[kt][4 + j] = (_Float16)x1[j];
            }
        }
        f4v c[NT];
#pragma unroll
        for (int nt = 0; nt < NT; nt++) c[nt] = (f4v){0.f, 0.f, 0.f, 0.f};
#pragma unroll
        for (int kt = 0; kt < 2; kt++)
#pragma unroll
            for (int nt = 0; nt < NT; nt++)
                c[nt] = __builtin_amdgcn_mfma_f32_16x16x32_f16(af[kt], bf[nt][kt],
                                                               c[nt], 0, 0, 0);
#pragma unroll
        for (int reg = 0; reg < 4; reg++) {
            int r = m0 + quad * 4 + reg;
            if (r < N) {
#pragma unroll
                for (int nt = 0; nt < NT; nt++)
                    H[(size_t)r * 64 + nt * 16 + c16] = (_Float16)c[nt][reg];
            }
        }
        float ps[4], pd[4];
#pragma unroll
        for (int reg = 0; reg < 4; reg++) {
            ps[reg] = 0.f;
            pd[reg] = 0.f;
#pragma unroll
            for (int nt = 0; nt < NT; nt++) {
                ps[reg] = fmaf(c[nt][reg], asv[nt], ps[reg]);
                pd[reg] = fmaf(c[nt][reg], adv[nt], pd[reg]);
            }
        }
        for (int o = 1; o < 16; o <<= 1) {
#pragma unroll
            for (int reg = 0; reg < 4; reg++) {
                ps[reg] += __shfl_xor(ps[reg], o, 64);
                pd[reg] += __shfl_xor(pd[reg], o, 64);
            }
        }
        if (c16 == 0) {
#pragma unroll
            for (int reg = 0; reg < 4; reg++) {
                int r = m0 + quad * 4 + reg;
                if (r < N) {
                    asb[r] = ps[reg];
                    adb[r] = pd[reg];
                }
            }
        }
    }
}

// ---------------- fused: bucket histogram + layer-1 GEMM -------------------
// Blocks [0,histBlocks) run the dst histogram; the rest run gemm1 (x@W1),
// which is independent of the CSR-build chain — co-resident, not serial.
__global__ __launch_bounds__(256) void k_hist_gemm(
    const int* __restrict__ dst, int E, int nb, int* __restrict__ bcount,
    int histBlocks,
    const float* __restrict__ X, const float* __restrict__ W,
    const float* __restrict__ a_s, const float* __restrict__ a_d, int N,
    _Float16* __restrict__ H, float* __restrict__ asb, float* __restrict__ adb) {
    __shared__ int h[BKT_SZ];
    int bid = blockIdx.x;
    if (bid < histBlocks) {
        for (int i = threadIdx.x; i < nb; i += 256) h[i] = 0;
        __syncthreads();
        for (int i = bid * 256 + threadIdx.x; i < E; i += histBlocks * 256)
            atomicAdd(&h[dst[i] >> BKT_BITS], 1);
        __syncthreads();
        for (int i = threadIdx.x; i < nb; i += 256)
            if (h[i]) atomicAdd(&bcount[i], h[i]);
    } else {
        gemm64_body(bid - histBlocks, (int)gridDim.x - histBlocks, X, W, a_s, a_d,
                    N, H, asb, adb);
    }
}

// ---------------- standalone GEMM (layers 2,3) -----------------------------
template <int FP>
__global__ __launch_bounds__(256) void k_gemm(
    const float* __restrict__ X, const float* __restrict__ W,
    const float* __restrict__ a_s, const float* __restrict__ a_d,
    int N, int Freal,
    _Float16* __restrict__ H, float* __restrict__ asb, float* __restrict__ adb) {
    constexpr int NT = FP / 16;  // 16-col tiles
    int lane = threadIdx.x & 63;
    int quad = lane >> 4;
    int c16 = lane & 15;

    h8v bf[NT][2];
    float asv[NT], adv[NT];
#pragma unroll
    for (int nt = 0; nt < NT; nt++) {
        int n = nt * 16 + c16;
        bool ok = (n < Freal);
        asv[nt] = ok ? a_s[n] : 0.f;
        adv[nt] = ok ? a_d[n] : 0.f;
#pragma unroll
        for (int kt = 0; kt < 2; kt++)
#pragma unroll
            for (int j = 0; j < 8; j++) {
                int k = kt * 32 + quad * 8 + j;
                bf[nt][kt][j] = (_Float16)(ok ? W[k * Freal + n] : 0.f);
            }
    }

    int wid = (blockIdx.x * blockDim.x + threadIdx.x) >> 6;
    int nw = (gridDim.x * blockDim.x) >> 6;
    int ntile = (N + 15) >> 4;

    for (int t = wid; t < ntile; t += nw) {
        int m0 = t << 4;
        int row = m0 + c16;
        const float* xr = X + (size_t)min(row, N - 1) * 64;
        h8v af[2];
#pragma unroll
        for (int kt = 0; kt < 2; kt++) {
            f4v x0 = *(const f4v*)(xr + kt * 32 + quad * 8);
            f4v x1 = *(const f4v*)(xr + kt * 32 + quad * 8 + 4);
#pragma unroll
            for (int j = 0; j < 4; j++) {
                af[kt][j] = (_Float16)x0[j];
                af[kt][4 + j] = (_Float16)x1[j];
            }
        }
        f4v c[NT];
#pragma unroll
        for (int nt = 0; nt < NT; nt++) c[nt] = (f4v){0.f, 0.f, 0.f, 0.f};
#pragma unroll
        for (int kt = 0; kt < 2; kt++)
#pragma unroll
            for (int nt = 0; nt < NT; nt++)
                c[nt] = __builtin_amdgcn_mfma_f32_16x16x32_f16(af[kt], bf[nt][kt],
                                                               c[nt], 0, 0, 0);
#pragma unroll
        for (int reg = 0; reg < 4; reg++) {
            int r = m0 + quad * 4 + reg;
            if (r < N) {
#pragma unroll
                for (int nt = 0; nt < NT; nt++)
                    H[(size_t)r * FP + nt * 16 + c16] = (_Float16)c[nt][reg];
            }
        }
        float ps[4], pd[4];
#pragma unroll
        for (int reg = 0; reg < 4; reg++) {
            ps[reg] = 0.f;
            pd[reg] = 0.f;
#pragma unroll
            for (int nt = 0; nt < NT; nt++) {
                ps[reg] = fmaf(c[nt][reg], asv[nt], ps[reg]);
                pd[reg] = fmaf(c[nt][reg], adv[nt], pd[reg]);
            }
        }
        for (int o = 1; o < 16; o <<= 1) {
#pragma unroll
            for (int reg = 0; reg < 4; reg++) {
                ps[reg] += __shfl_xor(ps[reg], o, 64);
                pd[reg] += __shfl_xor(pd[reg], o, 64);
            }
        }
        if (c16 == 0) {
#pragma unroll
            for (int reg = 0; reg < 4; reg++) {
                int r = m0 + quad * 4 + reg;
                if (r < N) {
                    asb[r] = ps[reg];
                    adb[r] = pd[reg];
                }
            }
        }
    }
}

// ---------------- slow-path agg (R4-proven, whole wave, any deg) -----------
template <int FP>
__device__ __forceinline__ void agg_slow(
    int node, const _Float16* __restrict__ H, const float* __restrict__ asb,
    const float* __restrict__ adb, const float* __restrict__ bias,
    const int* __restrict__ rowptr, const int* __restrict__ csr,
    int N, int Freal, float* __restrict__ out, int mode, int lane) {
    if (node >= N) return;
    int start = rowptr[node];
    int end = rowptr[node + 1];
    float ad = adb[node];
    int lf = lane & (FP - 1);
    const float NEG_INF = -__builtin_inff();

    float m = NEG_INF;
    for (int base = start; base < end; base += 64) {
        int i = base + lane;
        if (i < end) {
            float t = asb[csr[i]] + ad;
            float e = (t > 0.f) ? t : NEG_SLOPE * t;
            m = fmaxf(m, e);
        }
    }
    for (int o = 32; o > 0; o >>= 1) m = fmaxf(m, __shfl_xor(m, o, 64));
    float dsum = 0.f, acc = 0.f;
    for (int base = start; base < end; base += 64) {
        int i = base + lane;
        int cnt = min(64, end - base);
        int s = 0;
        float p = 0.f;
        if (i < end) {
            s = csr[i];
            float t = asb[s] + ad;
            float e = (t > 0.f) ? t : NEG_SLOPE * t;
            p = __expf(e - m);
        }
        dsum += p;
        for (int j = 0; j < cnt; j++) {
            float pj = __shfl(p, j, 64);
            int sj = __shfl(s, j, 64);
            acc = fmaf(pj, (float)H[(size_t)sj * FP + lf], acc);
        }
    }
    for (int o = 32; o > 0; o >>= 1) dsum += __shfl_xor(dsum, o, 64);

    float b = (lf < Freal) ? bias[lf] : 0.f;
    float z = acc / dsum + b;
    if (mode == 0) {
        if (lane < FP) out[(size_t)node * FP + lane] = fmaxf(z, 0.f);
    } else {
        float zz = (lane < Freal) ? z : NEG_INF;
        float zm = zz;
        for (int o = 32; o > 0; o >>= 1) zm = fmaxf(zm, __shfl_xor(zm, o, 64));
        float ez = (lane < Freal) ? __expf(zz - zm) : 0.f;
        float es = ez;
        for (int o = 32; o > 0; o >>= 1) es += __shfl_xor(es, o, 64);
        if (lane < Freal) out[(size_t)node * Freal + lane] = zz - zm - __logf(es);
    }
}

// ---------------- Aggregation: dual-node wave, vector gather (R10) ---------
// Half h of the wave owns node 2*wid+h (deg<=32 fast path). Scores + max/
// dsum butterflies within the 32-lane half (offsets 16..1). Gather: LPR
// lanes/row, GRPH=32/LPR rows in flight per half, W halfs (2W bytes)/lane.
// R13: unroll 4 (32 rows in flight per wave). Loop bound degm is
// wave-uniform; shuffles unconditional, in-half; overshoot lanes p=0,s=0.
template <int FP, int W>
__global__ __launch_bounds__(256) void k_agg(
    const _Float16* __restrict__ H, const float* __restrict__ asb,
    const float* __restrict__ adb, const float* __restrict__ bias,
    const int* __restrict__ rowptr, const int* __restrict__ csr,
    int N, int Freal, float* __restrict__ out, int mode) {
    constexpr int LPR = FP / W;    // lanes per row (within a half)
    constexpr int GRPH = 32 / LPR; // rows in flight per half
    using vecW = typename std::conditional<W == 8, h8v, h4v>::type;
    int lane = threadIdx.x & 63;
    int half = lane >> 5;
    int li = lane & 31;
    int wid = (blockIdx.x * blockDim.x + threadIdx.x) >> 6;
    int nA = 2 * wid;
    if (nA >= N) return;
    int n = nA + half;
    bool valid = (n < N);
    int start = 0, end = 0;
    float ad = 0.f;
    if (valid) {
        start = rowptr[n];
        end = rowptr[n + 1];
        ad = adb[n];
    }
    int deg = end - start;
    int degm = max(deg, __shfl_xor(deg, 32, 64));  // wave-uniform

    const float NEG_INF = -__builtin_inff();

    if (degm <= 32) {
        int g = li / LPR;   // row-group within half
        int fl = li % LPR;  // vecW slot within row
        int s = 0;
        float e = NEG_INF;
        if (li < deg) {
            s = csr[start + li];
            float t = asb[s] + ad;
            e = (t > 0.f) ? t : NEG_SLOPE * t;
        }
        float m = e;
        for (int o = 16; o > 0; o >>= 1) m = fmaxf(m, __shfl_xor(m, o, 64));
        float p = (li < deg) ? __expf(e - m) : 0.f;
        float dsum = p;
        for (int o = 16; o > 0; o >>= 1) dsum += __shfl_xor(dsum, o, 64);

        float acc[W];
#pragma unroll
        for (int c = 0; c < W; c++) acc[c] = 0.f;
#pragma unroll 4
        for (int jb = 0; jb < degm; jb += GRPH) {  // wave-uniform bound
            int gidx = half * 32 + jb + g;         // in-half, <= half*32+31
            float pj = __shfl(p, gidx, 64);        // 0 for jb+g >= deg
            int sj = __shfl(s, gidx, 64);          // 0 for jb+g >= deg
            vecW r = ((const vecW*)(H + (size_t)sj * FP))[fl];
#pragma unroll
            for (int c = 0; c < W; c++) acc[c] = fmaf(pj, (float)r[c], acc[c]);
        }
        // cross-group butterfly within half: offsets LPR..16 preserve fl
        for (int o = LPR; o < 32; o <<= 1) {
#pragma unroll
            for (int c = 0; c < W; c++) acc[c] += __shfl_xor(acc[c], o, 64);
        }
        float inv = 1.f / dsum;
        int fbase = fl * W;

        if (mode == 0) {
            if (valid && li < LPR) {
                float z[W];
#pragma unroll
                for (int c = 0; c < W; c++)
                    z[c] = fmaxf(fmaf(acc[c], inv, bias[fbase + c]), 0.f);
                float4* op = (float4*)(out + (size_t)n * FP + fbase);
#pragma unroll
                for (int q = 0; q < W / 4; q++)
                    op[q] = make_float4(z[4 * q], z[4 * q + 1], z[4 * q + 2],
                                        z[4 * q + 3]);
            }
        } else {
            float zc[W];
#pragma unroll
            for (int c = 0; c < W; c++) {
                int f = fbase + c;
                zc[c] = (f < Freal) ? fmaf(acc[c], inv, bias[f]) : NEG_INF;
            }
            float vm = zc[0];
#pragma unroll
            for (int c = 1; c < W; c++) vm = fmaxf(vm, zc[c]);
            for (int o = 1; o < LPR; o <<= 1) vm = fmaxf(vm, __shfl_xor(vm, o, 64));
            float es = 0.f;
#pragma unroll
            for (int c = 0; c < W; c++) es += __expf(zc[c] - vm);
            for (int o = 1; o < LPR; o <<= 1) es += __shfl_xor(es, o, 64);
            float ls = __logf(es);
            if (valid && li < LPR) {
#pragma unroll
                for (int c = 0; c < W; c++) {
                    int f = fbase + c;
                    if (f < Freal) out[(size_t)n * Freal + f] = zc[c] - vm - ls;
                }
            }
        }
    } else {
        // rare (P(deg>32) ~ 2e-4): whole-wave per node, R4-proven path
        agg_slow<FP>(nA, H, asb, adb, bias, rowptr, csr, N, Freal, out, mode, lane);
        agg_slow<FP>(nA + 1, H, asb, adb, bias, rowptr, csr, N, Freal, out, mode, lane);
    }
}

// ---------------------------------------------------------------------------
extern "C" void kernel_launch(void* const* d_in, const int* in_sizes, int n_in,
                              void* d_out, int out_size, void* d_ws, size_t ws_size,
                              hipStream_t stream) {
    const float* x = (const float*)d_in[0];
    const int* ei = (const int*)d_in[1];
    const float* W1 = (const float*)d_in[2];
    const float* a1s = (const float*)d_in[3];
    const float* a1d = (const float*)d_in[4];
    const float* b1 = (const float*)d_in[5];
    const float* W2 = (const float*)d_in[6];
    const float* a2s = (const float*)d_in[7];
    const float* a2d = (const float*)d_in[8];
    const float* b2 = (const float*)d_in[9];
    const float* W3 = (const float*)d_in[10];
    const float* a3s = (const float*)d_in[11];
    const float* a3d = (const float*)d_in[12];
    const float* b3 = (const float*)d_in[13];

    const int N = in_sizes[0] / 64;
    const int E = in_sizes[1] / 2;
    const int Etot = E + N;
    const int nb = (N + BKT_SZ - 1) >> BKT_BITS;  // buckets of 512 nodes
    const int* srcv = ei;
    const int* dstv = ei + E;

    // workspace carve (256B aligned)
    size_t off = 0;
    char* base = (char*)d_ws;
    auto carve = [&](size_t bytes) -> void* {
        void* p = base + off;
        off = (off + bytes + 255) & ~(size_t)255;
        return p;
    };
    int* bcount = (int*)carve((size_t)(nb + 1) * 4);
    int* ebase = (int*)carve((size_t)(nb + 1) * 4);
    int* gcur = (int*)carve((size_t)nb * 4);
    int* rowptr = (int*)carve((size_t)(N + 1) * 4);
    int* csr = (int*)carve((size_t)Etot * 4);
    float* asb = (float*)carve((size_t)N * 4);
    float* adb = (float*)carve((size_t)N * 4);
    _Float16* hA = (_Float16*)carve((size_t)N * 64 * 2);  // fp16 H (layers 1,2)
    float* fB = (float*)carve((size_t)N * 64 * 4);        // fp32 agg out / X
    _Float16* hC = (_Float16*)carve((size_t)N * 16 * 2);  // fp16 H (layer 3)
    // NOTE: ebuf no longer aliases hA (gemm1 writes hA concurrently with
    // bscatter writing ebuf) — ebuf gets its own carve region.
    int* ebuf = (int*)carve((size_t)E * 4);

    const int aggBlocks = (N + 7) / 8;  // 4 waves/block, 2 nodes/wave
    const int gemmBlocks = 784;        // 3136 waves, ~2 tiles (16 rows) each
    const int histBlocks = 512;

    // ---- CSR build (bucket sort) + layer-1 GEMM fused ----
    hipMemsetAsync(bcount, 0, (size_t)nb * 4, stream);
    k_hist_gemm<<<histBlocks + gemmBlocks, 256, 0, stream>>>(
        dstv, E, nb, bcount, histBlocks, x, W1, a1s, a1d, N, hA, asb, adb);
    k_bscan<<<1, BKT_SZ, 0, stream>>>(bcount, nb, E, N, ebase, gcur, rowptr);
    k_bscatter<<<(E + 8191) / 8192, 1024, 0, stream>>>(srcv, dstv, E, nb, gcur, ebuf);
    k_bcsr<<<nb, BKT_SZ, 0, stream>>>(ebuf, ebase, N, rowptr, csr);

    // ---- layer 1 aggregation ----
    k_agg<64, 8><<<aggBlocks, 256, 0, stream>>>(hA, asb, adb, b1, rowptr, csr, N, 64, fB, 0);
    // ---- layer 2 ----
    k_gemm<64><<<gemmBlocks, 256, 0, stream>>>(fB, W2, a2s, a2d, N, 64, hA, asb, adb);
    k_agg<64, 8><<<aggBlocks, 256, 0, stream>>>(hA, asb, adb, b2, rowptr, csr, N, 64, fB, 0);
    // ---- layer 3 ----
    k_gemm<16><<<gemmBlocks, 256, 0, stream>>>(fB, W3, a3s, a3d, N, 10, hC, asb, adb);
    k_agg<16, 4><<<aggBlocks, 256, 0, stream>>>(hC, asb, adb, b3, rowptr, csr, N, 10,
                                                (float*)d_out, 1);
}